// Round 3
// baseline (1405.218 us; speedup 1.0000x reference)
//
#include <hip/hip_runtime.h>
#include <math.h>

#define DM 2048      // model dim
#define NT 16384     // tokens = B*S
#define KD 2048      // GEMM K

typedef __bf16 bf16x8 __attribute__((ext_vector_type(8)));
typedef float  f32x4  __attribute__((ext_vector_type(4)));

__device__ __forceinline__ void gld_lds16(const void* g, void* l) {
  __builtin_amdgcn_global_load_lds(
      (const __attribute__((address_space(1))) unsigned int*)g,
      (__attribute__((address_space(3))) unsigned int*)l, 16, 0, 0);
}

// ---------------- cast fp32 -> bf16 (vectorized) ----------------
__global__ __launch_bounds__(256) void k_cast(const float* __restrict__ x,
                                              __bf16* __restrict__ y) {
  const size_t i = ((size_t)blockIdx.x * 256 + threadIdx.x) * 8;
  const float4 a = *(const float4*)(x + i);
  const float4 b = *(const float4*)(x + i + 4);
  bf16x8 o;
  o[0]=(__bf16)a.x; o[1]=(__bf16)a.y; o[2]=(__bf16)a.z; o[3]=(__bf16)a.w;
  o[4]=(__bf16)b.x; o[5]=(__bf16)b.y; o[6]=(__bf16)b.z; o[7]=(__bf16)b.w;
  *(bf16x8*)(y + i) = o;
}

// -------- transpose+cast: W (KDxN fp32 row-major, N=2048) -> Wt (N x KD bf16) --------
__global__ __launch_bounds__(256) void k_transpose(const float* __restrict__ W,
                                                   __bf16* __restrict__ Wt) {
  __shared__ float t[32][33];
  const int tx = threadIdx.x, ty = threadIdx.y;
  const int n  = blockIdx.x * 32 + tx;
  const int k0 = blockIdx.y * 32;
  #pragma unroll
  for (int j = 0; j < 32; j += 8) t[ty + j][tx] = W[(size_t)(k0 + ty + j) * DM + n];
  __syncthreads();
  const int kk = k0 + tx;
  const int n0 = blockIdx.x * 32;
  #pragma unroll
  for (int j = 0; j < 32; j += 8)
    Wt[(size_t)(n0 + ty + j) * KD + kk] = (__bf16)t[tx][ty + j];
}

// -------- concat 3 bias vectors (2048 each) into one 6144 --------
__global__ __launch_bounds__(256) void k_bias3(const float* __restrict__ a,
                                               const float* __restrict__ b,
                                               const float* __restrict__ c,
                                               float* __restrict__ o) {
  const int i = blockIdx.x * 256 + threadIdx.x;
  o[i] = (i < 2048) ? a[i] : ((i < 4096) ? b[i - 2048] : c[i - 4096]);
}

// ======== GEMM: 128x128 tile, BK=32, 4-slot LDS ring, 64 KiB STATIC LDS ========
// A: M x KD bf16 row-major.  Bt: N x KD bf16 row-major (B transposed).
// 4 waves (2x2), per-wave 64x64 output, acc[4][4] f32x4.
// Counted-vmcnt pipeline (T3+T4): while computing ring slot s, issue the 4
// global_load_lds for slot s+3; one "s_waitcnt vmcnt(8) + s_barrier" per
// K-step (vmcnt NEVER drained to 0 in the main loop; prefetch depth 3 slots).
// Ledger (4 loads/STAGE): prologue 12 -> wait(8) lands slot 0; steady state
// STAGE -> 12, wait(8) retires exactly the oldest slot -> slot s+1 landed
// before COMPUTE(s+1). Race-freedom: slot (s+3)&3 was last READ in
// COMPUTE(s-1); those ds_reads completed before that iteration's barrier
// (compiler lgkmcnt before the consuming MFMAs), and STAGE(s+3) is issued
// after it -> no overwrite race, with a single barrier per K-step.
// LDS layout LINEAR (no swizzle): 64 B rows -> the fragment ds_read_b128
// (16 rows x 4 k-blocks per wave) touches each bank exactly 8 words = the
// wave64 conflict-free floor. Staging is lane*16B contiguous (gld_lds
// requirement). T5 setprio around the MFMA cluster; T1 XCD-bijective block
// swizzle (all grids used are multiples of 8).
// modes: 0 bf16 out, 1 bf16 gelu out, 2 f32 out + f32 residual,
//        3 f32 out + bf16 residual.
__global__ __launch_bounds__(256, 2) void k_gemm(
    const __bf16* __restrict__ A, const __bf16* __restrict__ Bt,
    const float* __restrict__ bias, const int mode, const int ntile_n,
    const int NS,
    __bf16* __restrict__ outb, const float* __restrict__ resf,
    const __bf16* __restrict__ resb, float* __restrict__ outf) {
  __shared__ __bf16 lds[4 * 8192];  // 4 slots x (A 128x32 | B 128x32) = 64 KiB
  const int tid  = threadIdx.x;
  const int w = tid >> 6, lane = tid & 63;
  const int quad = lane >> 4, r16 = lane & 15;
  const int wm = (w >> 1) * 64, wn = (w & 1) * 64;

  // XCD-aware bijective swizzle (nwg % 8 == 0 for all our grids)
  const int nwg = gridDim.x;
  const int sw  = (blockIdx.x & 7) * (nwg >> 3) + (blockIdx.x >> 3);
  const int m0 = (sw / ntile_n) * 128;
  const int n0 = (sw % ntile_n) * 128;

  // staging: wave w covers rows [w*32, w*32+32) of A and of Bt.
  // lane l -> row w*32 + l/4, k-block l&3; lane elem offset = l*8 (linear).
  const int srow = (w << 5) + (lane >> 2);
  const __bf16* aSrc = A  + (size_t)(m0 + srow) * KD + (lane & 3) * 8;
  const __bf16* bSrc = Bt + (size_t)(n0 + srow) * KD + (lane & 3) * 8;

  // fragment read offsets (elements): row r at r*32, k-block quad at quad*8
  const int aoff = (wm + r16) * 32 + quad * 8;
  const int boff = 4096 + (wn + r16) * 32 + quad * 8;

  f32x4 acc[4][4] = {};

#define STAGE(q) { \
    const int so = ((q) & 3) * 8192; \
    gld_lds16(aSrc + (q) * 32,                   lds + so + (w << 10)); \
    gld_lds16(aSrc + (size_t)16 * KD + (q) * 32, lds + so + (w << 10) + 512); \
    gld_lds16(bSrc + (q) * 32,                   lds + so + 4096 + (w << 10)); \
    gld_lds16(bSrc + (size_t)16 * KD + (q) * 32, lds + so + 4096 + (w << 10) + 512); \
  }

#define COMPUTE(s) { \
    const int so = ((s) & 3) * 8192; \
    bf16x8 af[4], bfr[4]; \
    _Pragma("unroll") \
    for (int mi = 0; mi < 4; ++mi) af[mi] = *(const bf16x8*)&lds[so + aoff + mi * 512]; \
    _Pragma("unroll") \
    for (int ni = 0; ni < 4; ++ni) bfr[ni] = *(const bf16x8*)&lds[so + boff + ni * 512]; \
    __builtin_amdgcn_s_setprio(1); \
    _Pragma("unroll") \
    for (int mi = 0; mi < 4; ++mi) { \
      _Pragma("unroll") \
      for (int ni = 0; ni < 4; ++ni) \
        acc[mi][ni] = __builtin_amdgcn_mfma_f32_16x16x32_bf16(af[mi], bfr[ni], acc[mi][ni], 0, 0, 0); \
    } \
    __builtin_amdgcn_s_setprio(0); \
  }

#define WAITBAR(n) { \
    asm volatile("s_waitcnt vmcnt(" #n ")" ::: "memory"); \
    __builtin_amdgcn_s_barrier(); \
    asm volatile("" ::: "memory"); \
  }

  // prologue: 3 slots in flight; after the barrier slot 0 is fully landed
  STAGE(0) STAGE(1) STAGE(2)
  WAITBAR(8)

  // main loop: KD/32 = 64 K-steps
  for (int s = 0; s < 60; ++s) {
    STAGE(s + 3)
    COMPUTE(s)
    WAITBAR(8)
  }
  STAGE(63) COMPUTE(60) WAITBAR(8)
  COMPUTE(61) WAITBAR(4)
  COMPUTE(62) WAITBAR(0)
  COMPUTE(63)
  __syncthreads();  // drain before LDS reuse in epilogue

#undef STAGE
#undef COMPUTE
#undef WAITBAR

  // epilogue: C/D layout col=lane&15, row=(lane>>4)*4+reg
  if (mode <= 1) {
    // bf16 out: transpose through wave-private LDS chunk -> 16B coalesced stores
    __bf16* eb = &lds[w * 2048];  // 64x32 bf16 per wave
    #pragma unroll
    for (int half = 0; half < 2; half++) {
      #pragma unroll
      for (int nj = 0; nj < 2; nj++) {
        const int ni = half * 2 + nj;
        const int gn = n0 + wn + ni * 16 + r16;
        const float bv = bias[gn];
        #pragma unroll
        for (int mi = 0; mi < 4; mi++) {
          #pragma unroll
          for (int r = 0; r < 4; r++) {
            float v = acc[mi][ni][r] + bv;
            if (mode == 1) v = 0.5f * v * (1.0f + erff(v * 0.70710678118654752f));
            eb[(mi * 16 + quad * 4 + r) * 32 + nj * 16 + r16] = (__bf16)v;
          }
        }
      }
      // same-wave LDS write->read: compiler inserts lgkmcnt waits; no barrier
      #pragma unroll
      for (int rd = 0; rd < 4; rd++) {
        const int row = rd * 16 + (lane >> 2);
        const int c0 = (lane & 3) * 8;
        bf16x8 vv = *(const bf16x8*)&eb[row * 32 + c0];
        *(bf16x8*)(outb + (size_t)(m0 + wm + row) * NS + n0 + wn + half * 32 + c0) = vv;
      }
    }
  } else {
    // fp32 out (+residual): 16 lanes x 4B = full 64B lines already
    #pragma unroll
    for (int ni = 0; ni < 4; ni++) {
      const int gn = n0 + wn + ni * 16 + r16;
      const float bv = bias[gn];
      #pragma unroll
      for (int mi = 0; mi < 4; mi++) {
        const int gm = m0 + wm + mi * 16 + quad * 4;
        if (mode == 2) {
          #pragma unroll
          for (int r = 0; r < 4; r++) {
            const size_t o = (size_t)(gm + r) * NS + gn;
            outf[o] = acc[mi][ni][r] + bv + resf[o];
          }
        } else {
          #pragma unroll
          for (int r = 0; r < 4; r++) {
            const size_t o = (size_t)(gm + r) * NS + gn;
            outf[o] = acc[mi][ni][r] + bv + (float)resb[o];
          }
        }
      }
    }
  }
}

// -------- per-token head-attention + residual + LN1 (one block per token) --------
// QKV: NT x 6144 bf16 (q | k | v per token row)
__global__ __launch_bounds__(256) void k_attn_ln1(
    const __bf16* __restrict__ QKV, const float* __restrict__ X,
    const float* __restrict__ g1, const float* __restrict__ be1,
    float* __restrict__ X1, __bf16* __restrict__ X1b, const int use_f32) {
  __shared__ float qs[16 * 132];  // stride 132 breaks 16-way bank conflicts
  __shared__ float ks[16 * 132];
  __shared__ float vs[16 * 132];
  __shared__ float p[256];
  __shared__ float red[8];
  const int tid = threadIdx.x;
  const size_t qbase = (size_t)blockIdx.x * 6144;
  const size_t base  = (size_t)blockIdx.x * DM;
  const int e0 = tid * 8;

  {  // load q,k,v rows -> LDS fp32
    const int row = e0 >> 7, c0 = e0 & 127;
    bf16x8 qv = *(const bf16x8*)(QKV + qbase + e0);
    bf16x8 kv = *(const bf16x8*)(QKV + qbase + 2048 + e0);
    bf16x8 vv = *(const bf16x8*)(QKV + qbase + 4096 + e0);
    #pragma unroll
    for (int j = 0; j < 8; j++) {
      qs[row * 132 + c0 + j] = (float)qv[j];
      ks[row * 132 + c0 + j] = (float)kv[j];
      vs[row * 132 + c0 + j] = (float)vv[j];
    }
  }
  __syncthreads();

  {  // scores + softmax over t (16 lanes per head)
    const int h = tid >> 4, t = tid & 15;
    const float* qp = &qs[h * 132];
    const float* kp = &ks[t * 132];
    float s = 0.f;
    #pragma unroll
    for (int d = 0; d < 128; d++) s += qp[d] * kp[d];
    s *= 0.08838834764831845f;  // 1/sqrt(128)
    float mx = s;
    #pragma unroll
    for (int off = 8; off; off >>= 1) mx = fmaxf(mx, __shfl_xor(mx, off, 16));
    const float e = expf(s - mx);
    float sum = e;
    #pragma unroll
    for (int off = 8; off; off >>= 1) sum += __shfl_xor(sum, off, 16);
    p[tid] = e / sum;
  }
  __syncthreads();

  // y = att @ v ; z = X + y ; LN partials
  float zloc[8];
  float zs = 0.f, zq = 0.f;
  {
    const float4 x1 = *(const float4*)(X + base + e0);
    const float4 x2 = *(const float4*)(X + base + e0 + 4);
    const float xr[8] = {x1.x, x1.y, x1.z, x1.w, x2.x, x2.y, x2.z, x2.w};
    const int hh = e0 >> 7;
    const int d0 = e0 & 127;
    const float* pp = &p[hh * 16];
    #pragma unroll
    for (int j = 0; j < 8; j++) {
      float y = 0.f;
      #pragma unroll
      for (int t2 = 0; t2 < 16; t2++) y += pp[t2] * vs[t2 * 132 + d0 + j];
      const float z = xr[j] + y;
      zloc[j] = z; zs += z; zq += z * z;
    }
  }
  #pragma unroll
  for (int off = 32; off; off >>= 1) {
    zs += __shfl_xor(zs, off, 64);
    zq += __shfl_xor(zq, off, 64);
  }
  const int wave = tid >> 6, lane = tid & 63;
  if (lane == 0) { red[wave] = zs; red[4 + wave] = zq; }
  __syncthreads();
  zs = red[0] + red[1] + red[2] + red[3];
  zq = red[4] + red[5] + red[6] + red[7];
  const float mean = zs * (1.f / DM);
  const float var = zq * (1.f / DM) - mean * mean;
  const float rstd = rsqrtf(var + 1e-5f);
  {
    float o[8];
    #pragma unroll
    for (int j = 0; j < 8; j++)
      o[j] = (zloc[j] - mean) * rstd * g1[e0 + j] + be1[e0 + j];
    if (use_f32) {
      *(float4*)(X1 + base + e0)     = make_float4(o[0], o[1], o[2], o[3]);
      *(float4*)(X1 + base + e0 + 4) = make_float4(o[4], o[5], o[6], o[7]);
    }
    bf16x8 ob;
    #pragma unroll
    for (int j = 0; j < 8; j++) ob[j] = (__bf16)o[j];
    *(bf16x8*)(X1b + base + e0) = ob;
  }
}

// ---------------- final LN2 (one block per token) ----------------
__global__ __launch_bounds__(256) void k_ln2(const float* __restrict__ Z,
                                             const float* __restrict__ g,
                                             const float* __restrict__ be,
                                             float* __restrict__ out) {
  __shared__ float red[8];
  const int tid = threadIdx.x;
  const size_t base = (size_t)blockIdx.x * DM;
  const int e0 = tid * 8;
  const float4 a = *(const float4*)(Z + base + e0);
  const float4 b = *(const float4*)(Z + base + e0 + 4);
  float z[8] = {a.x, a.y, a.z, a.w, b.x, b.y, b.z, b.w};
  float zs = 0.f, zq = 0.f;
  #pragma unroll
  for (int j = 0; j < 8; j++) { zs += z[j]; zq += z[j] * z[j]; }
  #pragma unroll
  for (int off = 32; off; off >>= 1) {
    zs += __shfl_xor(zs, off, 64);
    zq += __shfl_xor(zq, off, 64);
  }
  const int wave = tid >> 6, lane = tid & 63;
  if (lane == 0) { red[wave] = zs; red[4 + wave] = zq; }
  __syncthreads();
  zs = red[0] + red[1] + red[2] + red[3];
  zq = red[4] + red[5] + red[6] + red[7];
  const float mean = zs * (1.f / DM);
  const float var = zq * (1.f / DM) - mean * mean;
  const float rstd = rsqrtf(var + 1e-5f);
  float o[8];
  #pragma unroll
  for (int j = 0; j < 8; j++)
    o[j] = (z[j] - mean) * rstd * g[e0 + j] + be[e0 + j];
  *(float4*)(out + base + e0)     = make_float4(o[0], o[1], o[2], o[3]);
  *(float4*)(out + base + e0 + 4) = make_float4(o[4], o[5], o[6], o[7]);
}

extern "C" void kernel_launch(void* const* d_in, const int* in_sizes, int n_in,
                              void* d_out, int out_size, void* d_ws, size_t ws_size,
                              hipStream_t stream) {
  const float* X   = (const float*)d_in[0];
  const float* Wq  = (const float*)d_in[1];
  const float* bq  = (const float*)d_in[2];
  const float* Wk  = (const float*)d_in[3];
  const float* bk  = (const float*)d_in[4];
  const float* Wv  = (const float*)d_in[5];
  const float* bv  = (const float*)d_in[6];
  const float* g1  = (const float*)d_in[7];
  const float* be1 = (const float*)d_in[8];
  const float* W1  = (const float*)d_in[9];
  const float* b1  = (const float*)d_in[10];
  const float* W2  = (const float*)d_in[11];
  const float* b2  = (const float*)d_in[12];
  const float* g2  = (const float*)d_in[13];
  const float* be2 = (const float*)d_in[14];
  float* out = (float*)d_out;

  char* ws = (char*)d_ws;
  size_t off = 0;
  auto alloc = [&](size_t b) -> char* {
    char* p = ws + off;
    off += (b + 255) & ~(size_t)255;
    return p;
  };
  const size_t EL  = (size_t)NT * DM;
  const size_t EL3 = (size_t)NT * 6144;
  __bf16* Xb    = (__bf16*)alloc(EL * 2);
  __bf16* Wqkvt = (__bf16*)alloc((size_t)6144 * KD * 2);  // [Wq^T | Wk^T | Wv^T]
  __bf16* W1t   = (__bf16*)alloc((size_t)DM * KD * 2);
  __bf16* W2t   = (__bf16*)alloc((size_t)DM * KD * 2);
  float*  b3    = (float*)alloc(6144 * 4);
  __bf16* QKVb  = (__bf16*)alloc(EL3 * 2);
  __bf16* X1b   = (__bf16*)alloc(EL * 2);
  // fp32 X1 residual if workspace allows; else fall back to bf16 residual
  const int use_f32 = (ws_size >= off + EL * 4) ? 1 : 0;
  float* X1 = nullptr;
  if (use_f32) X1 = (float*)alloc(EL * 4);
  __bf16* Hb = Xb;            // h reuses Xb (dead after QKV GEMM)
  float*  Z  = (float*)QKVb;  // Z (fp32, 128MB) reuses QKVb (192MB, dead after attn)

  k_cast<<<dim3(NT * DM / 2048), dim3(256), 0, stream>>>(X, Xb);
  dim3 tb(32, 8), tg(64, 64);
  k_transpose<<<tg, tb, 0, stream>>>(Wq, Wqkvt);
  k_transpose<<<tg, tb, 0, stream>>>(Wk, Wqkvt + (size_t)2048 * KD);
  k_transpose<<<tg, tb, 0, stream>>>(Wv, Wqkvt + (size_t)4096 * KD);
  k_transpose<<<tg, tb, 0, stream>>>(W1, W1t);
  k_transpose<<<tg, tb, 0, stream>>>(W2, W2t);
  k_bias3<<<dim3(24), dim3(256), 0, stream>>>(bq, bk, bv, b3);

  // fused QKV GEMM: M=16384, N=6144 -> 128x48 = 6144 blocks
  k_gemm<<<dim3((NT / 128) * 48), dim3(256), 0, stream>>>(
      Xb, Wqkvt, b3, 0, 48, 6144, QKVb, nullptr, nullptr, nullptr);
  k_attn_ln1<<<dim3(NT), dim3(256), 0, stream>>>(QKVb, X, g1, be1, X1, X1b, use_f32);
  // FFN1 (+GELU): M=16384, N=2048 -> 128x16 = 2048 blocks
  k_gemm<<<dim3((NT / 128) * 16), dim3(256), 0, stream>>>(
      X1b, W1t, b1, 1, 16, 2048, Hb, nullptr, nullptr, nullptr);
  // FFN2 (+bias +residual, fp32 out)
  k_gemm<<<dim3((NT / 128) * 16), dim3(256), 0, stream>>>(
      Hb, W2t, b2, use_f32 ? 2 : 3, 16, 2048, nullptr, X1, X1b, Z);
  k_ln2<<<dim3(NT), dim3(256), 0, stream>>>(Z, g2, be2, out);
}

// Round 4
// 1313.518 us; speedup vs baseline: 1.0698x; 1.0698x over previous
//
#include <hip/hip_runtime.h>
#include <math.h>

#define DM 2048      // model dim
#define NT 16384     // tokens = B*S
#define KD 2048      // GEMM K

typedef __bf16 bf16x8 __attribute__((ext_vector_type(8)));
typedef float  f32x4  __attribute__((ext_vector_type(4)));

__device__ __forceinline__ void gld_lds16(const void* g, void* l) {
  __builtin_amdgcn_global_load_lds(
      (const __attribute__((address_space(1))) unsigned int*)g,
      (__attribute__((address_space(3))) unsigned int*)l, 16, 0, 0);
}

// ---------------- cast fp32 -> bf16 (vectorized) ----------------
__global__ __launch_bounds__(256) void k_cast(const float* __restrict__ x,
                                              __bf16* __restrict__ y) {
  const size_t i = ((size_t)blockIdx.x * 256 + threadIdx.x) * 8;
  const float4 a = *(const float4*)(x + i);
  const float4 b = *(const float4*)(x + i + 4);
  bf16x8 o;
  o[0]=(__bf16)a.x; o[1]=(__bf16)a.y; o[2]=(__bf16)a.z; o[3]=(__bf16)a.w;
  o[4]=(__bf16)b.x; o[5]=(__bf16)b.y; o[6]=(__bf16)b.z; o[7]=(__bf16)b.w;
  *(bf16x8*)(y + i) = o;
}

// -------- transpose+cast: W (KDxN fp32 row-major, N=2048) -> Wt (N x KD bf16) --------
__global__ __launch_bounds__(256) void k_transpose(const float* __restrict__ W,
                                                   __bf16* __restrict__ Wt) {
  __shared__ float t[32][33];
  const int tx = threadIdx.x, ty = threadIdx.y;
  const int n  = blockIdx.x * 32 + tx;
  const int k0 = blockIdx.y * 32;
  #pragma unroll
  for (int j = 0; j < 32; j += 8) t[ty + j][tx] = W[(size_t)(k0 + ty + j) * DM + n];
  __syncthreads();
  const int kk = k0 + tx;
  const int n0 = blockIdx.x * 32;
  #pragma unroll
  for (int j = 0; j < 32; j += 8)
    Wt[(size_t)(n0 + ty + j) * KD + kk] = (__bf16)t[tx][ty + j];
}

// -------- concat 3 bias vectors (2048 each) into one 6144 --------
__global__ __launch_bounds__(256) void k_bias3(const float* __restrict__ a,
                                               const float* __restrict__ b,
                                               const float* __restrict__ c,
                                               float* __restrict__ o) {
  const int i = blockIdx.x * 256 + threadIdx.x;
  o[i] = (i < 2048) ? a[i] : ((i < 4096) ? b[i - 2048] : c[i - 4096]);
}

// ======== GEMM: 128x128 tile, BK=32, 4-slot LDS ring, 64 KiB STATIC LDS ========
// A: M x KD bf16 row-major.  Bt: N x KD bf16 row-major (B transposed).
// 4 waves (2x2), per-wave 64x64 output, acc[4][4] f32x4.
// Counted-vmcnt pipeline (T3+T4): while computing ring slot s, issue the 4
// global_load_lds for slot s+3; one "s_waitcnt vmcnt(8) + s_barrier" per
// K-step (vmcnt NEVER drained to 0 in the main loop; prefetch depth 3 slots).
// Ledger (4 loads/STAGE): prologue 12 -> wait(8) lands slot 0; steady state
// STAGE -> 12, wait(8) retires exactly the oldest slot. Race-freedom: slot
// (s+3)&3 was last READ in COMPUTE(s-1); those ds_reads completed before that
// iteration's barrier (compiler lgkmcnt before the consuming MFMAs), and
// STAGE(s+3) is issued after it.
// LDS XOR swizzle (T2, rule #21 both-sides): global k-block kb of row r is
// stored at LDS slot kb ^ ((r>>1)&3), achieved by inverse-swizzling the GLOBAL
// source address (LDS dest stays linear, as gld_lds requires). Fragment
// ds_read_b128 then has every consecutive 8-lane group covering all 8
// 16B-bank-groups exactly once -> conflict-free. (Round-3's linear layout put
// 8 lanes on 2 bank-groups: 17x bank-conflict counter, ~15% cycle tax.)
// NO XCD block swizzle: round-3 proved it destroys L2/LLC panel reuse here
// (FETCH 0.41->1.61 GB). Plain bid -> (m = bid/ntile_n, n = bid%ntile_n),
// N-fastest (round-0's verified 93%-cache-absorbed ordering).
// T5 setprio around the MFMA cluster.
// modes: 0 bf16 out, 1 bf16 gelu out, 2 f32 out + f32 residual,
//        3 f32 out + bf16 residual.
__global__ __launch_bounds__(256, 2) void k_gemm(
    const __bf16* __restrict__ A, const __bf16* __restrict__ Bt,
    const float* __restrict__ bias, const int mode, const int ntile_n,
    const int NS,
    __bf16* __restrict__ outb, const float* __restrict__ resf,
    const __bf16* __restrict__ resb, float* __restrict__ outf) {
  __shared__ __bf16 lds[4 * 8192];  // 4 slots x (A 128x32 | B 128x32) = 64 KiB
  const int tid  = threadIdx.x;
  const int w = tid >> 6, lane = tid & 63;
  const int quad = lane >> 4, r16 = lane & 15;
  const int wm = (w >> 1) * 64, wn = (w & 1) * 64;

  const int m0 = (blockIdx.x / ntile_n) * 128;
  const int n0 = (blockIdx.x % ntile_n) * 128;

  // staging: wave w covers rows [w*32, w*32+32) of A and of Bt.
  // lane l -> row w*32 + l/4, LDS slot l&3 holding global k-block
  // (l&3)^((l>>3)&3)  [ = (l&3)^((srow>>1)&3) since w*16 ≡ 0 mod 4 ]
  const int srow = (w << 5) + (lane >> 2);
  const int kbs  = (lane & 3) ^ ((lane >> 3) & 3);
  const __bf16* aSrc = A  + (size_t)(m0 + srow) * KD + kbs * 8;
  const __bf16* bSrc = Bt + (size_t)(n0 + srow) * KD + kbs * 8;

  // fragment read: global k-block quad of row r lives at LDS slot
  // quad ^ ((r>>1)&3); fragment rows differ by 16 -> (r>>1)&3 == (r16>>1)&3
  const int kbl  = quad ^ ((r16 >> 1) & 3);
  const int aoff = (wm + r16) * 32 + kbl * 8;
  const int boff = 4096 + (wn + r16) * 32 + kbl * 8;

  f32x4 acc[4][4] = {};

#define STAGE(q) { \
    const int so = ((q) & 3) * 8192; \
    gld_lds16(aSrc + (q) * 32,                   lds + so + (w << 10)); \
    gld_lds16(aSrc + (size_t)16 * KD + (q) * 32, lds + so + (w << 10) + 512); \
    gld_lds16(bSrc + (q) * 32,                   lds + so + 4096 + (w << 10)); \
    gld_lds16(bSrc + (size_t)16 * KD + (q) * 32, lds + so + 4096 + (w << 10) + 512); \
  }

#define COMPUTE(s) { \
    const int so = ((s) & 3) * 8192; \
    bf16x8 af[4], bfr[4]; \
    _Pragma("unroll") \
    for (int mi = 0; mi < 4; ++mi) af[mi] = *(const bf16x8*)&lds[so + aoff + mi * 512]; \
    _Pragma("unroll") \
    for (int ni = 0; ni < 4; ++ni) bfr[ni] = *(const bf16x8*)&lds[so + boff + ni * 512]; \
    __builtin_amdgcn_s_setprio(1); \
    _Pragma("unroll") \
    for (int mi = 0; mi < 4; ++mi) { \
      _Pragma("unroll") \
      for (int ni = 0; ni < 4; ++ni) \
        acc[mi][ni] = __builtin_amdgcn_mfma_f32_16x16x32_bf16(af[mi], bfr[ni], acc[mi][ni], 0, 0, 0); \
    } \
    __builtin_amdgcn_s_setprio(0); \
  }

#define WAITBAR(n) { \
    asm volatile("s_waitcnt vmcnt(" #n ")" ::: "memory"); \
    __builtin_amdgcn_s_barrier(); \
    asm volatile("" ::: "memory"); \
  }

  // prologue: 3 slots in flight; after the barrier slot 0 is fully landed
  STAGE(0) STAGE(1) STAGE(2)
  WAITBAR(8)

  // main loop: KD/32 = 64 K-steps
  for (int s = 0; s < 60; ++s) {
    STAGE(s + 3)
    COMPUTE(s)
    WAITBAR(8)
  }
  STAGE(63) COMPUTE(60) WAITBAR(8)
  COMPUTE(61) WAITBAR(4)
  COMPUTE(62) WAITBAR(0)
  COMPUTE(63)
  __syncthreads();  // drain before LDS reuse in epilogue

#undef STAGE
#undef COMPUTE
#undef WAITBAR

  // epilogue: C/D layout col=lane&15, row=(lane>>4)*4+reg
  if (mode <= 1) {
    // bf16 out: transpose through wave-private LDS chunk -> 16B coalesced stores
    __bf16* eb = &lds[w * 2048];  // 64x32 bf16 per wave
    #pragma unroll
    for (int half = 0; half < 2; half++) {
      #pragma unroll
      for (int nj = 0; nj < 2; nj++) {
        const int ni = half * 2 + nj;
        const int gn = n0 + wn + ni * 16 + r16;
        const float bv = bias[gn];
        #pragma unroll
        for (int mi = 0; mi < 4; mi++) {
          #pragma unroll
          for (int r = 0; r < 4; r++) {
            float v = acc[mi][ni][r] + bv;
            if (mode == 1) v = 0.5f * v * (1.0f + erff(v * 0.70710678118654752f));
            eb[(mi * 16 + quad * 4 + r) * 32 + nj * 16 + r16] = (__bf16)v;
          }
        }
      }
      // same-wave LDS write->read: compiler inserts lgkmcnt waits; no barrier
      #pragma unroll
      for (int rd = 0; rd < 4; rd++) {
        const int row = rd * 16 + (lane >> 2);
        const int c0 = (lane & 3) * 8;
        bf16x8 vv = *(const bf16x8*)&eb[row * 32 + c0];
        *(bf16x8*)(outb + (size_t)(m0 + wm + row) * NS + n0 + wn + half * 32 + c0) = vv;
      }
    }
  } else {
    // fp32 out (+residual): 16 lanes x 4B = full 64B lines already
    #pragma unroll
    for (int ni = 0; ni < 4; ni++) {
      const int gn = n0 + wn + ni * 16 + r16;
      const float bv = bias[gn];
      #pragma unroll
      for (int mi = 0; mi < 4; mi++) {
        const int gm = m0 + wm + mi * 16 + quad * 4;
        if (mode == 2) {
          #pragma unroll
          for (int r = 0; r < 4; r++) {
            const size_t o = (size_t)(gm + r) * NS + gn;
            outf[o] = acc[mi][ni][r] + bv + resf[o];
          }
        } else {
          #pragma unroll
          for (int r = 0; r < 4; r++) {
            const size_t o = (size_t)(gm + r) * NS + gn;
            outf[o] = acc[mi][ni][r] + bv + (float)resb[o];
          }
        }
      }
    }
  }
}

// -------- per-token head-attention + residual + LN1 (one block per token) --------
// QKV: NT x 6144 bf16 (q | k | v per token row)
__global__ __launch_bounds__(256) void k_attn_ln1(
    const __bf16* __restrict__ QKV, const float* __restrict__ X,
    const float* __restrict__ g1, const float* __restrict__ be1,
    float* __restrict__ X1, __bf16* __restrict__ X1b, const int use_f32) {
  __shared__ float qs[16 * 132];  // stride 132 breaks 16-way bank conflicts
  __shared__ float ks[16 * 132];
  __shared__ float vs[16 * 132];
  __shared__ float p[256];
  __shared__ float red[8];
  const int tid = threadIdx.x;
  const size_t qbase = (size_t)blockIdx.x * 6144;
  const size_t base  = (size_t)blockIdx.x * DM;
  const int e0 = tid * 8;

  {  // load q,k,v rows -> LDS fp32
    const int row = e0 >> 7, c0 = e0 & 127;
    bf16x8 qv = *(const bf16x8*)(QKV + qbase + e0);
    bf16x8 kv = *(const bf16x8*)(QKV + qbase + 2048 + e0);
    bf16x8 vv = *(const bf16x8*)(QKV + qbase + 4096 + e0);
    #pragma unroll
    for (int j = 0; j < 8; j++) {
      qs[row * 132 + c0 + j] = (float)qv[j];
      ks[row * 132 + c0 + j] = (float)kv[j];
      vs[row * 132 + c0 + j] = (float)vv[j];
    }
  }
  __syncthreads();

  {  // scores + softmax over t (16 lanes per head)
    const int h = tid >> 4, t = tid & 15;
    const float* qp = &qs[h * 132];
    const float* kp = &ks[t * 132];
    float s = 0.f;
    #pragma unroll
    for (int d = 0; d < 128; d++) s += qp[d] * kp[d];
    s *= 0.08838834764831845f;  // 1/sqrt(128)
    float mx = s;
    #pragma unroll
    for (int off = 8; off; off >>= 1) mx = fmaxf(mx, __shfl_xor(mx, off, 16));
    const float e = expf(s - mx);
    float sum = e;
    #pragma unroll
    for (int off = 8; off; off >>= 1) sum += __shfl_xor(sum, off, 16);
    p[tid] = e / sum;
  }
  __syncthreads();

  // y = att @ v ; z = X + y ; LN partials
  float zloc[8];
  float zs = 0.f, zq = 0.f;
  {
    const float4 x1 = *(const float4*)(X + base + e0);
    const float4 x2 = *(const float4*)(X + base + e0 + 4);
    const float xr[8] = {x1.x, x1.y, x1.z, x1.w, x2.x, x2.y, x2.z, x2.w};
    const int hh = e0 >> 7;
    const int d0 = e0 & 127;
    const float* pp = &p[hh * 16];
    #pragma unroll
    for (int j = 0; j < 8; j++) {
      float y = 0.f;
      #pragma unroll
      for (int t2 = 0; t2 < 16; t2++) y += pp[t2] * vs[t2 * 132 + d0 + j];
      const float z = xr[j] + y;
      zloc[j] = z; zs += z; zq += z * z;
    }
  }
  #pragma unroll
  for (int off = 32; off; off >>= 1) {
    zs += __shfl_xor(zs, off, 64);
    zq += __shfl_xor(zq, off, 64);
  }
  const int wave = tid >> 6, lane = tid & 63;
  if (lane == 0) { red[wave] = zs; red[4 + wave] = zq; }
  __syncthreads();
  zs = red[0] + red[1] + red[2] + red[3];
  zq = red[4] + red[5] + red[6] + red[7];
  const float mean = zs * (1.f / DM);
  const float var = zq * (1.f / DM) - mean * mean;
  const float rstd = rsqrtf(var + 1e-5f);
  {
    float o[8];
    #pragma unroll
    for (int j = 0; j < 8; j++)
      o[j] = (zloc[j] - mean) * rstd * g1[e0 + j] + be1[e0 + j];
    if (use_f32) {
      *(float4*)(X1 + base + e0)     = make_float4(o[0], o[1], o[2], o[3]);
      *(float4*)(X1 + base + e0 + 4) = make_float4(o[4], o[5], o[6], o[7]);
    }
    bf16x8 ob;
    #pragma unroll
    for (int j = 0; j < 8; j++) ob[j] = (__bf16)o[j];
    *(bf16x8*)(X1b + base + e0) = ob;
  }
}

// ---------------- final LN2 (one block per token) ----------------
__global__ __launch_bounds__(256) void k_ln2(const float* __restrict__ Z,
                                             const float* __restrict__ g,
                                             const float* __restrict__ be,
                                             float* __restrict__ out) {
  __shared__ float red[8];
  const int tid = threadIdx.x;
  const size_t base = (size_t)blockIdx.x * DM;
  const int e0 = tid * 8;
  const float4 a = *(const float4*)(Z + base + e0);
  const float4 b = *(const float4*)(Z + base + e0 + 4);
  float z[8] = {a.x, a.y, a.z, a.w, b.x, b.y, b.z, b.w};
  float zs = 0.f, zq = 0.f;
  #pragma unroll
  for (int j = 0; j < 8; j++) { zs += z[j]; zq += z[j] * z[j]; }
  #pragma unroll
  for (int off = 32; off; off >>= 1) {
    zs += __shfl_xor(zs, off, 64);
    zq += __shfl_xor(zq, off, 64);
  }
  const int wave = tid >> 6, lane = tid & 63;
  if (lane == 0) { red[wave] = zs; red[4 + wave] = zq; }
  __syncthreads();
  zs = red[0] + red[1] + red[2] + red[3];
  zq = red[4] + red[5] + red[6] + red[7];
  const float mean = zs * (1.f / DM);
  const float var = zq * (1.f / DM) - mean * mean;
  const float rstd = rsqrtf(var + 1e-5f);
  float o[8];
  #pragma unroll
  for (int j = 0; j < 8; j++)
    o[j] = (z[j] - mean) * rstd * g[e0 + j] + be[e0 + j];
  *(float4*)(out + base + e0)     = make_float4(o[0], o[1], o[2], o[3]);
  *(float4*)(out + base + e0 + 4) = make_float4(o[4], o[5], o[6], o[7]);
}

extern "C" void kernel_launch(void* const* d_in, const int* in_sizes, int n_in,
                              void* d_out, int out_size, void* d_ws, size_t ws_size,
                              hipStream_t stream) {
  const float* X   = (const float*)d_in[0];
  const float* Wq  = (const float*)d_in[1];
  const float* bq  = (const float*)d_in[2];
  const float* Wk  = (const float*)d_in[3];
  const float* bk  = (const float*)d_in[4];
  const float* Wv  = (const float*)d_in[5];
  const float* bv  = (const float*)d_in[6];
  const float* g1  = (const float*)d_in[7];
  const float* be1 = (const float*)d_in[8];
  const float* W1  = (const float*)d_in[9];
  const float* b1  = (const float*)d_in[10];
  const float* W2  = (const float*)d_in[11];
  const float* b2  = (const float*)d_in[12];
  const float* g2  = (const float*)d_in[13];
  const float* be2 = (const float*)d_in[14];
  float* out = (float*)d_out;

  char* ws = (char*)d_ws;
  size_t off = 0;
  auto alloc = [&](size_t b) -> char* {
    char* p = ws + off;
    off += (b + 255) & ~(size_t)255;
    return p;
  };
  const size_t EL  = (size_t)NT * DM;
  const size_t EL3 = (size_t)NT * 6144;
  __bf16* Xb    = (__bf16*)alloc(EL * 2);
  __bf16* Wqkvt = (__bf16*)alloc((size_t)6144 * KD * 2);  // [Wq^T | Wk^T | Wv^T]
  __bf16* W1t   = (__bf16*)alloc((size_t)DM * KD * 2);
  __bf16* W2t   = (__bf16*)alloc((size_t)DM * KD * 2);
  float*  b3    = (float*)alloc(6144 * 4);
  __bf16* QKVb  = (__bf16*)alloc(EL3 * 2);
  __bf16* X1b   = (__bf16*)alloc(EL * 2);
  // fp32 X1 residual if workspace allows; else fall back to bf16 residual
  const int use_f32 = (ws_size >= off + EL * 4) ? 1 : 0;
  float* X1 = nullptr;
  if (use_f32) X1 = (float*)alloc(EL * 4);
  __bf16* Hb = Xb;            // h reuses Xb (dead after QKV GEMM)
  float*  Z  = (float*)QKVb;  // Z (fp32, 128MB) reuses QKVb (192MB, dead after attn)

  k_cast<<<dim3(NT * DM / 2048), dim3(256), 0, stream>>>(X, Xb);
  dim3 tb(32, 8), tg(64, 64);
  k_transpose<<<tg, tb, 0, stream>>>(Wq, Wqkvt);
  k_transpose<<<tg, tb, 0, stream>>>(Wk, Wqkvt + (size_t)2048 * KD);
  k_transpose<<<tg, tb, 0, stream>>>(Wv, Wqkvt + (size_t)4096 * KD);
  k_transpose<<<tg, tb, 0, stream>>>(W1, W1t);
  k_transpose<<<tg, tb, 0, stream>>>(W2, W2t);
  k_bias3<<<dim3(24), dim3(256), 0, stream>>>(bq, bk, bv, b3);

  // fused QKV GEMM: M=16384, N=6144 -> 128x48 = 6144 blocks
  k_gemm<<<dim3((NT / 128) * 48), dim3(256), 0, stream>>>(
      Xb, Wqkvt, b3, 0, 48, 6144, QKVb, nullptr, nullptr, nullptr);
  k_attn_ln1<<<dim3(NT), dim3(256), 0, stream>>>(QKVb, X, g1, be1, X1, X1b, use_f32);
  // FFN1 (+GELU): M=16384, N=2048 -> 128x16 = 2048 blocks
  k_gemm<<<dim3((NT / 128) * 16), dim3(256), 0, stream>>>(
      X1b, W1t, b1, 1, 16, 2048, Hb, nullptr, nullptr, nullptr);
  // FFN2 (+bias +residual, fp32 out)
  k_gemm<<<dim3((NT / 128) * 16), dim3(256), 0, stream>>>(
      Hb, W2t, b2, use_f32 ? 2 : 3, 16, 2048, nullptr, X1, X1b, Z);
  k_ln2<<<dim3(NT), dim3(256), 0, stream>>>(Z, g2, be2, out);
}

// Round 5
// 1251.583 us; speedup vs baseline: 1.1228x; 1.0495x over previous
//
#include <hip/hip_runtime.h>
#include <math.h>

#define DM 2048      // model dim
#define NT 16384     // tokens = B*S
#define KD 2048      // GEMM K

typedef __bf16 bf16x8 __attribute__((ext_vector_type(8)));
typedef float  f32x4  __attribute__((ext_vector_type(4)));

__device__ __forceinline__ void gld_lds16(const void* g, void* l) {
  __builtin_amdgcn_global_load_lds(
      (const __attribute__((address_space(1))) unsigned int*)g,
      (__attribute__((address_space(3))) unsigned int*)l, 16, 0, 0);
}

// ---------------- cast fp32 -> bf16 (vectorized) ----------------
__global__ __launch_bounds__(256) void k_cast(const float* __restrict__ x,
                                              __bf16* __restrict__ y) {
  const size_t i = ((size_t)blockIdx.x * 256 + threadIdx.x) * 8;
  const float4 a = *(const float4*)(x + i);
  const float4 b = *(const float4*)(x + i + 4);
  bf16x8 o;
  o[0]=(__bf16)a.x; o[1]=(__bf16)a.y; o[2]=(__bf16)a.z; o[3]=(__bf16)a.w;
  o[4]=(__bf16)b.x; o[5]=(__bf16)b.y; o[6]=(__bf16)b.z; o[7]=(__bf16)b.w;
  *(bf16x8*)(y + i) = o;
}

// -------- transpose+cast: W (KDxN fp32 row-major, N=2048) -> Wt (N x KD bf16) --------
__global__ __launch_bounds__(256) void k_transpose(const float* __restrict__ W,
                                                   __bf16* __restrict__ Wt) {
  __shared__ float t[32][33];
  const int tx = threadIdx.x, ty = threadIdx.y;
  const int n  = blockIdx.x * 32 + tx;
  const int k0 = blockIdx.y * 32;
  #pragma unroll
  for (int j = 0; j < 32; j += 8) t[ty + j][tx] = W[(size_t)(k0 + ty + j) * DM + n];
  __syncthreads();
  const int kk = k0 + tx;
  const int n0 = blockIdx.x * 32;
  #pragma unroll
  for (int j = 0; j < 32; j += 8)
    Wt[(size_t)(n0 + ty + j) * KD + kk] = (__bf16)t[tx][ty + j];
}

// -------- concat 3 bias vectors (2048 each) into one 6144 --------
__global__ __launch_bounds__(256) void k_bias3(const float* __restrict__ a,
                                               const float* __restrict__ b,
                                               const float* __restrict__ c,
                                               float* __restrict__ o) {
  const int i = blockIdx.x * 256 + threadIdx.x;
  o[i] = (i < 2048) ? a[i] : ((i < 4096) ? b[i - 2048] : c[i - 4096]);
}

// ======== GEMM: 256x256 tile, BK=32, 4-slot LDS ring, 128 KiB STATIC LDS ========
// A: M x KD bf16 row-major.  Bt: N x KD bf16 row-major (B transposed).
// 512 threads / 8 waves (2 M x 4 N), per-wave 128x64 output, acc[8][4] f32x4.
// Counted-vmcnt pipeline (T3+T4), ledger hardware-verified in R4: per K-step
// STAGE(s+3) [4 gld_lds/wave] -> COMPUTE(s) [32 MFMA] -> s_waitcnt vmcnt(8)
// + s_barrier. Entering step s: slots s+1,s+2 outstanding (8); wait(8) at end
// of s-1 retired slot s. vmcnt never drains to 0 in the loop; prefetch depth
// 3 K-tiles (~600+ cyc of compute) covers L2/most-HBM latency. Race-freedom:
// slot (s+3)&3 was last READ in COMPUTE(s-1), whose ds_reads completed before
// that step's barrier; STAGE(s+3) issues after it.
// vs R4 (128x2/BK=32, 503us): 2x MFMA per barrier (32 vs 16), 2x B-panel
// L2 reuse. vs R0 (446us): stage-ahead + counted waits instead of the
// vmcnt(0) drain that capped MfmaUtil at 43%.
// LDS XOR swizzle (T2, rule #21 both-sides, verified R4): global k-block kb
// of row r stored at LDS slot kb ^ ((r>>1)&3) via inverse-swizzled GLOBAL
// source (LDS dest linear, as gld_lds requires). Fragment ds_read_b128:
// every consecutive 8-lane group covers all 8 16B bank-groups -> conflict-free.
// NO XCD block swizzle (R3: it quadrupled FETCH). Plain N-fastest ordering.
// T5 setprio around the MFMA cluster.
// modes: 0 bf16 out, 1 bf16 gelu out, 2 f32 out + f32 residual,
//        3 f32 out + bf16 residual.
__global__ __launch_bounds__(512, 2) void k_gemm(
    const __bf16* __restrict__ A, const __bf16* __restrict__ Bt,
    const float* __restrict__ bias, const int mode, const int ntile_n,
    const int NS,
    __bf16* __restrict__ outb, const float* __restrict__ resf,
    const __bf16* __restrict__ resb, float* __restrict__ outf) {
  __shared__ __bf16 lds[4 * 16384];  // 4 slots x (A 256x32 | B 256x32) = 128 KiB
  const int tid  = threadIdx.x;
  const int w = tid >> 6, lane = tid & 63;
  const int quad = lane >> 4, r16 = lane & 15;
  const int wr = w >> 2, wc = w & 3;

  const int m0 = (blockIdx.x / ntile_n) * 256;
  const int n0 = (blockIdx.x % ntile_n) * 256;

  // staging: wave w covers rows [w*32, w*32+32) of A and of Bt.
  // lane l -> row w*32 + l/4 (+16 for 2nd inst), LDS slot l&3 holding global
  // k-block (l&3)^((l>>3)&3)  [ (srow>>1)&3 == (l>>3)&3 since w*16, i*8 ≡ 0 mod 4 ]
  const int srow = (w << 5) + (lane >> 2);
  const int kbs  = (lane & 3) ^ ((lane >> 3) & 3);
  const __bf16* aSrc = A  + (size_t)(m0 + srow) * KD + kbs * 8;
  const __bf16* bSrc = Bt + (size_t)(n0 + srow) * KD + kbs * 8;

  // fragment read: global k-block quad of row r lives at LDS slot
  // quad ^ ((r>>1)&3); fragment rows differ by 16 -> (r>>1)&3 == (r16>>1)&3
  const int kbl  = quad ^ ((r16 >> 1) & 3);
  const int aoff = (wr * 128 + r16) * 32 + kbl * 8;          // + mi*512
  const int boff = 8192 + (wc * 64 + r16) * 32 + kbl * 8;    // + ni*512

  f32x4 acc[8][4] = {};

#define STAGE(q) { \
    const int so = ((q) & 3) * 16384; \
    gld_lds16(aSrc + (q) * 32,                   lds + so + (w << 10)); \
    gld_lds16(aSrc + (size_t)16 * KD + (q) * 32, lds + so + (w << 10) + 512); \
    gld_lds16(bSrc + (q) * 32,                   lds + so + 8192 + (w << 10)); \
    gld_lds16(bSrc + (size_t)16 * KD + (q) * 32, lds + so + 8192 + (w << 10) + 512); \
  }

#define COMPUTE(s) { \
    const int so = ((s) & 3) * 16384; \
    bf16x8 af[8], bfr[4]; \
    _Pragma("unroll") \
    for (int mi = 0; mi < 8; ++mi) af[mi] = *(const bf16x8*)&lds[so + aoff + mi * 512]; \
    _Pragma("unroll") \
    for (int ni = 0; ni < 4; ++ni) bfr[ni] = *(const bf16x8*)&lds[so + boff + ni * 512]; \
    __builtin_amdgcn_s_setprio(1); \
    _Pragma("unroll") \
    for (int mi = 0; mi < 8; ++mi) { \
      _Pragma("unroll") \
      for (int ni = 0; ni < 4; ++ni) \
        acc[mi][ni] = __builtin_amdgcn_mfma_f32_16x16x32_bf16(af[mi], bfr[ni], acc[mi][ni], 0, 0, 0); \
    } \
    __builtin_amdgcn_s_setprio(0); \
  }

#define WAITBAR(n) { \
    asm volatile("s_waitcnt vmcnt(" #n ")" ::: "memory"); \
    __builtin_amdgcn_s_barrier(); \
    asm volatile("" ::: "memory"); \
  }

  // prologue: 3 slots in flight; after the barrier slot 0 is fully landed
  STAGE(0) STAGE(1) STAGE(2)
  WAITBAR(8)

  // main loop: KD/32 = 64 K-steps
  for (int s = 0; s < 60; ++s) {
    STAGE(s + 3)
    COMPUTE(s)
    WAITBAR(8)
  }
  STAGE(63) COMPUTE(60) WAITBAR(8)
  COMPUTE(61) WAITBAR(4)
  COMPUTE(62) WAITBAR(0)
  COMPUTE(63)
  __syncthreads();  // drain before LDS reuse in epilogue

#undef STAGE
#undef COMPUTE
#undef WAITBAR

  // epilogue: C/D layout col=lane&15, row=(lane>>4)*4+reg
  if (mode <= 1) {
    // bf16 out: transpose through wave-private LDS chunk -> 16B coalesced stores
    __bf16* eb = &lds[w * 4096];  // 128x32 bf16 per wave
    #pragma unroll
    for (int half = 0; half < 2; half++) {
      #pragma unroll
      for (int nj = 0; nj < 2; nj++) {
        const int ni = half * 2 + nj;
        const int gn = n0 + wc * 64 + ni * 16 + r16;
        const float bv = bias[gn];
        #pragma unroll
        for (int mi = 0; mi < 8; mi++) {
          #pragma unroll
          for (int r = 0; r < 4; r++) {
            float v = acc[mi][ni][r] + bv;
            if (mode == 1) v = 0.5f * v * (1.0f + erff(v * 0.70710678118654752f));
            eb[(mi * 16 + quad * 4 + r) * 32 + nj * 16 + r16] = (__bf16)v;
          }
        }
      }
      // same-wave LDS write->read: compiler inserts lgkmcnt waits; no barrier
      #pragma unroll
      for (int rd = 0; rd < 8; rd++) {
        const int row = rd * 16 + (lane >> 2);
        const int c0 = (lane & 3) * 8;
        bf16x8 vv = *(const bf16x8*)&eb[row * 32 + c0];
        *(bf16x8*)(outb + (size_t)(m0 + wr * 128 + row) * NS + n0 + wc * 64 + half * 32 + c0) = vv;
      }
    }
  } else {
    // fp32 out (+residual): 16 lanes x 4B = full 64B lines already
    #pragma unroll
    for (int ni = 0; ni < 4; ni++) {
      const int gn = n0 + wc * 64 + ni * 16 + r16;
      const float bv = bias[gn];
      #pragma unroll
      for (int mi = 0; mi < 8; mi++) {
        const int gm = m0 + wr * 128 + mi * 16 + quad * 4;
        if (mode == 2) {
          #pragma unroll
          for (int r = 0; r < 4; r++) {
            const size_t o = (size_t)(gm + r) * NS + gn;
            outf[o] = acc[mi][ni][r] + bv + resf[o];
          }
        } else {
          #pragma unroll
          for (int r = 0; r < 4; r++) {
            const size_t o = (size_t)(gm + r) * NS + gn;
            outf[o] = acc[mi][ni][r] + bv + (float)resb[o];
          }
        }
      }
    }
  }
}

// -------- per-token head-attention + residual + LN1 (one block per token) --------
// QKV: NT x 6144 bf16 (q | k | v per token row)
__global__ __launch_bounds__(256) void k_attn_ln1(
    const __bf16* __restrict__ QKV, const float* __restrict__ X,
    const float* __restrict__ g1, const float* __restrict__ be1,
    float* __restrict__ X1, __bf16* __restrict__ X1b, const int use_f32) {
  __shared__ float qs[16 * 132];  // stride 132 breaks 16-way bank conflicts
  __shared__ float ks[16 * 132];
  __shared__ float vs[16 * 132];
  __shared__ float p[256];
  __shared__ float red[8];
  const int tid = threadIdx.x;
  const size_t qbase = (size_t)blockIdx.x * 6144;
  const size_t base  = (size_t)blockIdx.x * DM;
  const int e0 = tid * 8;

  {  // load q,k,v rows -> LDS fp32
    const int row = e0 >> 7, c0 = e0 & 127;
    bf16x8 qv = *(const bf16x8*)(QKV + qbase + e0);
    bf16x8 kv = *(const bf16x8*)(QKV + qbase + 2048 + e0);
    bf16x8 vv = *(const bf16x8*)(QKV + qbase + 4096 + e0);
    #pragma unroll
    for (int j = 0; j < 8; j++) {
      qs[row * 132 + c0 + j] = (float)qv[j];
      ks[row * 132 + c0 + j] = (float)kv[j];
      vs[row * 132 + c0 + j] = (float)vv[j];
    }
  }
  __syncthreads();

  {  // scores + softmax over t (16 lanes per head)
    const int h = tid >> 4, t = tid & 15;
    const float* qp = &qs[h * 132];
    const float* kp = &ks[t * 132];
    float s = 0.f;
    #pragma unroll
    for (int d = 0; d < 128; d++) s += qp[d] * kp[d];
    s *= 0.08838834764831845f;  // 1/sqrt(128)
    float mx = s;
    #pragma unroll
    for (int off = 8; off; off >>= 1) mx = fmaxf(mx, __shfl_xor(mx, off, 16));
    const float e = expf(s - mx);
    float sum = e;
    #pragma unroll
    for (int off = 8; off; off >>= 1) sum += __shfl_xor(sum, off, 16);
    p[tid] = e / sum;
  }
  __syncthreads();

  // y = att @ v ; z = X + y ; LN partials
  float zloc[8];
  float zs = 0.f, zq = 0.f;
  {
    const float4 x1 = *(const float4*)(X + base + e0);
    const float4 x2 = *(const float4*)(X + base + e0 + 4);
    const float xr[8] = {x1.x, x1.y, x1.z, x1.w, x2.x, x2.y, x2.z, x2.w};
    const int hh = e0 >> 7;
    const int d0 = e0 & 127;
    const float* pp = &p[hh * 16];
    #pragma unroll
    for (int j = 0; j < 8; j++) {
      float y = 0.f;
      #pragma unroll
      for (int t2 = 0; t2 < 16; t2++) y += pp[t2] * vs[t2 * 132 + d0 + j];
      const float z = xr[j] + y;
      zloc[j] = z; zs += z; zq += z * z;
    }
  }
  #pragma unroll
  for (int off = 32; off; off >>= 1) {
    zs += __shfl_xor(zs, off, 64);
    zq += __shfl_xor(zq, off, 64);
  }
  const int wave = tid >> 6, lane = tid & 63;
  if (lane == 0) { red[wave] = zs; red[4 + wave] = zq; }
  __syncthreads();
  zs = red[0] + red[1] + red[2] + red[3];
  zq = red[4] + red[5] + red[6] + red[7];
  const float mean = zs * (1.f / DM);
  const float var = zq * (1.f / DM) - mean * mean;
  const float rstd = rsqrtf(var + 1e-5f);
  {
    float o[8];
    #pragma unroll
    for (int j = 0; j < 8; j++)
      o[j] = (zloc[j] - mean) * rstd * g1[e0 + j] + be1[e0 + j];
    if (use_f32) {
      *(float4*)(X1 + base + e0)     = make_float4(o[0], o[1], o[2], o[3]);
      *(float4*)(X1 + base + e0 + 4) = make_float4(o[4], o[5], o[6], o[7]);
    }
    bf16x8 ob;
    #pragma unroll
    for (int j = 0; j < 8; j++) ob[j] = (__bf16)o[j];
    *(bf16x8*)(X1b + base + e0) = ob;
  }
}

// ---------------- final LN2 (one block per token) ----------------
__global__ __launch_bounds__(256) void k_ln2(const float* __restrict__ Z,
                                             const float* __restrict__ g,
                                             const float* __restrict__ be,
                                             float* __restrict__ out) {
  __shared__ float red[8];
  const int tid = threadIdx.x;
  const size_t base = (size_t)blockIdx.x * DM;
  const int e0 = tid * 8;
  const float4 a = *(const float4*)(Z + base + e0);
  const float4 b = *(const float4*)(Z + base + e0 + 4);
  float z[8] = {a.x, a.y, a.z, a.w, b.x, b.y, b.z, b.w};
  float zs = 0.f, zq = 0.f;
  #pragma unroll
  for (int j = 0; j < 8; j++) { zs += z[j]; zq += z[j] * z[j]; }
  #pragma unroll
  for (int off = 32; off; off >>= 1) {
    zs += __shfl_xor(zs, off, 64);
    zq += __shfl_xor(zq, off, 64);
  }
  const int wave = tid >> 6, lane = tid & 63;
  if (lane == 0) { red[wave] = zs; red[4 + wave] = zq; }
  __syncthreads();
  zs = red[0] + red[1] + red[2] + red[3];
  zq = red[4] + red[5] + red[6] + red[7];
  const float mean = zs * (1.f / DM);
  const float var = zq * (1.f / DM) - mean * mean;
  const float rstd = rsqrtf(var + 1e-5f);
  float o[8];
  #pragma unroll
  for (int j = 0; j < 8; j++)
    o[j] = (z[j] - mean) * rstd * g[e0 + j] + be[e0 + j];
  *(float4*)(out + base + e0)     = make_float4(o[0], o[1], o[2], o[3]);
  *(float4*)(out + base + e0 + 4) = make_float4(o[4], o[5], o[6], o[7]);
}

extern "C" void kernel_launch(void* const* d_in, const int* in_sizes, int n_in,
                              void* d_out, int out_size, void* d_ws, size_t ws_size,
                              hipStream_t stream) {
  const float* X   = (const float*)d_in[0];
  const float* Wq  = (const float*)d_in[1];
  const float* bq  = (const float*)d_in[2];
  const float* Wk  = (const float*)d_in[3];
  const float* bk  = (const float*)d_in[4];
  const float* Wv  = (const float*)d_in[5];
  const float* bv  = (const float*)d_in[6];
  const float* g1  = (const float*)d_in[7];
  const float* be1 = (const float*)d_in[8];
  const float* W1  = (const float*)d_in[9];
  const float* b1  = (const float*)d_in[10];
  const float* W2  = (const float*)d_in[11];
  const float* b2  = (const float*)d_in[12];
  const float* g2  = (const float*)d_in[13];
  const float* be2 = (const float*)d_in[14];
  float* out = (float*)d_out;

  char* ws = (char*)d_ws;
  size_t off = 0;
  auto alloc = [&](size_t b) -> char* {
    char* p = ws + off;
    off += (b + 255) & ~(size_t)255;
    return p;
  };
  const size_t EL  = (size_t)NT * DM;
  const size_t EL3 = (size_t)NT * 6144;
  __bf16* Xb    = (__bf16*)alloc(EL * 2);
  __bf16* Wqkvt = (__bf16*)alloc((size_t)6144 * KD * 2);  // [Wq^T | Wk^T | Wv^T]
  __bf16* W1t   = (__bf16*)alloc((size_t)DM * KD * 2);
  __bf16* W2t   = (__bf16*)alloc((size_t)DM * KD * 2);
  float*  b3    = (float*)alloc(6144 * 4);
  __bf16* QKVb  = (__bf16*)alloc(EL3 * 2);
  __bf16* X1b   = (__bf16*)alloc(EL * 2);
  // fp32 X1 residual if workspace allows; else fall back to bf16 residual
  const int use_f32 = (ws_size >= off + EL * 4) ? 1 : 0;
  float* X1 = nullptr;
  if (use_f32) X1 = (float*)alloc(EL * 4);
  __bf16* Hb = Xb;            // h reuses Xb (dead after QKV GEMM)
  float*  Z  = (float*)QKVb;  // Z (fp32, 128MB) reuses QKVb (192MB, dead after attn)

  k_cast<<<dim3(NT * DM / 2048), dim3(256), 0, stream>>>(X, Xb);
  dim3 tb(32, 8), tg(64, 64);
  k_transpose<<<tg, tb, 0, stream>>>(Wq, Wqkvt);
  k_transpose<<<tg, tb, 0, stream>>>(Wk, Wqkvt + (size_t)2048 * KD);
  k_transpose<<<tg, tb, 0, stream>>>(Wv, Wqkvt + (size_t)4096 * KD);
  k_transpose<<<tg, tb, 0, stream>>>(W1, W1t);
  k_transpose<<<tg, tb, 0, stream>>>(W2, W2t);
  k_bias3<<<dim3(24), dim3(256), 0, stream>>>(bq, bk, bv, b3);

  // fused QKV GEMM: M=16384, N=6144 -> 64x24 = 1536 blocks of 512 threads
  k_gemm<<<dim3((NT / 256) * 24), dim3(512), 0, stream>>>(
      Xb, Wqkvt, b3, 0, 24, 6144, QKVb, nullptr, nullptr, nullptr);
  k_attn_ln1<<<dim3(NT), dim3(256), 0, stream>>>(QKVb, X, g1, be1, X1, X1b, use_f32);
  // FFN1 (+GELU): M=16384, N=2048 -> 64x8 = 512 blocks
  k_gemm<<<dim3((NT / 256) * 8), dim3(512), 0, stream>>>(
      X1b, W1t, b1, 1, 8, 2048, Hb, nullptr, nullptr, nullptr);
  // FFN2 (+bias +residual, fp32 out)
  k_gemm<<<dim3((NT / 256) * 8), dim3(512), 0, stream>>>(
      Hb, W2t, b2, use_f32 ? 2 : 3, 8, 2048, nullptr, X1, X1b, Z);
  k_ln2<<<dim3(NT), dim3(256), 0, stream>>>(Z, g2, be2, out);
}